// Round 2
// baseline (1212.566 us; speedup 1.0000x reference)
//
#include <hip/hip_runtime.h>
#include <hip/hip_bf16.h>

// Problem constants
constexpr int Bc = 16, Sc = 512, Hc = 256, Vc = 8000, NHc = 4, HDc = 64;
constexpr int FFc = 512, Mc = 64;
constexpr int ROWS = Bc * Sc;      // 8192
constexpr int CH = 4 * Hc;         // 1024

typedef __attribute__((ext_vector_type(4))) float f32x4v;
typedef __attribute__((ext_vector_type(8))) short short8v;

// ---------------- embed + pos ----------------
__global__ __launch_bounds__(256) void k_embed(const int* __restrict__ ids,
                                               const float* __restrict__ emb,
                                               const float* __restrict__ pos,
                                               float* __restrict__ x) {
    const int r = blockIdx.x;          // 0..8191
    const int h = threadIdx.x;         // 0..255
    const int s = r & (Sc - 1);
    const int id = ids[r];
    x[(size_t)r * Hc + h] = emb[(size_t)id * Hc + h] + pos[(size_t)s * Hc + h];
}

// ---------------- fp32 GEMM 128x128, 8x8/thread: C = A[M,K] @ B[N,K]^T (+bias / gelu / scale) ----------------
// EPI: 0 = +bias, 1 = gelu(x+bias), 2 = x*0.125 (no bias)
// batch offset: z = blockIdx.z; ptr += (z>>2)*zH + (z&3)*zL
template <int EPI>
__global__ __launch_bounds__(256) void k_gemm128(const float* __restrict__ A,
                                                 const float* __restrict__ Bm,
                                                 const float* __restrict__ bias,
                                                 float* __restrict__ C,
                                                 int K, int lda, int ldb, int ldc,
                                                 long zAh, long zAl, long zBh, long zBl,
                                                 long zCh, long zCl) {
    __shared__ float As[16][132];
    __shared__ float Bs[16][132];
    const int z = blockIdx.z;
    const int z4 = z >> 2, zl = z & 3;
    A  += (size_t)z4 * zAh + (size_t)zl * zAl;
    Bm += (size_t)z4 * zBh + (size_t)zl * zBl;
    C  += (size_t)z4 * zCh + (size_t)zl * zCl;
    const int t = threadIdx.x;
    const int tm = blockIdx.x * 128, tn = blockIdx.y * 128;
    const int tx = t & 15, ty = t >> 4;
    float acc[8][8] = {};
    for (int kt = 0; kt < K; kt += 16) {
#pragma unroll
        for (int q = 0; q < 2; ++q) {
            const int f = t + q * 256;          // 0..511
            const int row = f >> 2, kc = (f & 3) * 4;
            const float4 av = *(const float4*)&A[(size_t)(tm + row) * lda + kt + kc];
            const float4 bv = *(const float4*)&Bm[(size_t)(tn + row) * ldb + kt + kc];
            As[kc + 0][row] = av.x; As[kc + 1][row] = av.y;
            As[kc + 2][row] = av.z; As[kc + 3][row] = av.w;
            const int sr = (row & 15) * 8 + (row >> 4);   // interleaved B layout
            Bs[kc + 0][sr] = bv.x; Bs[kc + 1][sr] = bv.y;
            Bs[kc + 2][sr] = bv.z; Bs[kc + 3][sr] = bv.w;
        }
        __syncthreads();
#pragma unroll
        for (int kk = 0; kk < 16; ++kk) {
            float a8[8], b8[8];
            *(float4*)&a8[0] = *(const float4*)&As[kk][ty * 8];
            *(float4*)&a8[4] = *(const float4*)&As[kk][ty * 8 + 4];
            // Bs interleave: element (tx*8 + r) holds column r*16 + tx
            *(float4*)&b8[0] = *(const float4*)&Bs[kk][tx * 8];
            *(float4*)&b8[4] = *(const float4*)&Bs[kk][tx * 8 + 4];
#pragma unroll
            for (int i = 0; i < 8; ++i)
#pragma unroll
                for (int j = 0; j < 8; ++j)
                    acc[i][j] = fmaf(a8[i], b8[j], acc[i][j]);
        }
        __syncthreads();
    }
#pragma unroll
    for (int i = 0; i < 8; ++i) {
        const size_t r = tm + ty * 8 + i;
#pragma unroll
        for (int j = 0; j < 8; ++j) {
            const int c = tn + j * 16 + tx;     // coalesced: 16 consecutive cols per lane group
            float v = acc[i][j];
            if (EPI == 0) v += bias[c];
            if (EPI == 1) { v += bias[c]; v = 0.5f * v * (1.0f + erff(v / 1.41421356237309515f)); }
            if (EPI == 2) v *= 0.125f;
            C[r * ldc + c] = v;
        }
    }
}

// ---------------- softmax over 512-wide rows ----------------
__global__ __launch_bounds__(256) void k_softmax(float* __restrict__ att) {
    float* p = att + (size_t)blockIdx.x * Sc;
    const int t = threadIdx.x;
    float v0 = p[t], v1 = p[t + 256];
    __shared__ float red[256];
    red[t] = fmaxf(v0, v1);
    __syncthreads();
    for (int s = 128; s > 0; s >>= 1) { if (t < s) red[t] = fmaxf(red[t], red[t + s]); __syncthreads(); }
    const float mx = red[0];
    __syncthreads();
    const float e0 = expf(v0 - mx), e1 = expf(v1 - mx);
    red[t] = e0 + e1;
    __syncthreads();
    for (int s = 128; s > 0; s >>= 1) { if (t < s) red[t] += red[t + s]; __syncthreads(); }
    const float sum = red[0];
    p[t] = e0 / sum;
    p[t + 256] = e1 / sum;
}

// ---------------- O = att @ V  (NN form), tile 128x64, 8 rows x 4 cols per thread ----------------
__global__ __launch_bounds__(256) void k_av128(const float* __restrict__ att,
                                               const float* __restrict__ qkv,
                                               float* __restrict__ O) {
    const int z = blockIdx.y;
    const int b = z >> 2, h = z & 3;
    const float* ab = att + (size_t)z * Sc * Sc;
    const float* vb = qkv + (size_t)b * Sc * (3 * Hc) + 2 * Hc + h * HDc;
    const int tm = blockIdx.x * 128;
    __shared__ float As[16][132];
    __shared__ float Vs[16][68];
    const int t = threadIdx.x, tx = t & 15, ty = t >> 4;
    float acc[8][4] = {};
    for (int kt = 0; kt < Sc; kt += 16) {
#pragma unroll
        for (int q = 0; q < 2; ++q) {
            const int f = t + q * 256;
            const int row = f >> 2, kc = (f & 3) * 4;
            const float4 av = *(const float4*)&ab[(size_t)(tm + row) * Sc + kt + kc];
            As[kc + 0][row] = av.x; As[kc + 1][row] = av.y;
            As[kc + 2][row] = av.z; As[kc + 3][row] = av.w;
        }
#pragma unroll
        for (int q = 0; q < 4; ++q) {
            const int f = t + q * 256;          // 0..1023
            const int kk = f >> 6, c = f & 63;
            Vs[kk][c] = vb[(size_t)(kt + kk) * (3 * Hc) + c];
        }
        __syncthreads();
#pragma unroll
        for (int kk = 0; kk < 16; ++kk) {
            float a8[8];
            *(float4*)&a8[0] = *(const float4*)&As[kk][ty * 8];
            *(float4*)&a8[4] = *(const float4*)&As[kk][ty * 8 + 4];
            float b4[4];
#pragma unroll
            for (int j = 0; j < 4; ++j) b4[j] = Vs[kk][tx + j * 16];
#pragma unroll
            for (int i = 0; i < 8; ++i)
#pragma unroll
                for (int j = 0; j < 4; ++j)
                    acc[i][j] = fmaf(a8[i], b4[j], acc[i][j]);
        }
        __syncthreads();
    }
#pragma unroll
    for (int i = 0; i < 8; ++i)
#pragma unroll
        for (int j = 0; j < 4; ++j)
            O[(size_t)(b * Sc + tm + ty * 8 + i) * Hc + h * HDc + tx + j * 16] = acc[i][j];
}

// ---------------- x = LayerNorm(x + res) * g + b ----------------
__global__ __launch_bounds__(256) void k_add_ln(float* __restrict__ x,
                                                const float* __restrict__ res,
                                                const float* __restrict__ g,
                                                const float* __restrict__ b) {
    const size_t row = blockIdx.x;
    const int t = threadIdx.x;
    float v = x[row * Hc + t] + res[row * Hc + t];
    __shared__ float red[256];
    red[t] = v;
    __syncthreads();
    for (int s = 128; s > 0; s >>= 1) { if (t < s) red[t] += red[t + s]; __syncthreads(); }
    const float mean = red[0] * (1.0f / 256.0f);
    __syncthreads();
    const float d = v - mean;
    red[t] = d * d;
    __syncthreads();
    for (int s = 128; s > 0; s >>= 1) { if (t < s) red[t] += red[t + s]; __syncthreads(); }
    const float var = red[0] * (1.0f / 256.0f);
    x[row * Hc + t] = d / sqrtf(var + 1e-5f) * g[t] + b[t];
}

// ---------------- LIF scan; writes 0/1 spikes (bf16-exact) into combined ----------------
__global__ __launch_bounds__(256) void k_lif(const float* __restrict__ proj,
                                             __hip_bfloat16* __restrict__ comb,
                                             int colOff) {
    const int b = blockIdx.x;
    const int h = threadIdx.x;
    const float* p = proj + (size_t)b * Sc * Hc + h;
    __hip_bfloat16* o = comb + (size_t)b * Sc * CH + colOff + h;
    float mem = 0.0f;
    for (int s0 = 0; s0 < Sc; s0 += 4) {
        float xs[4];
#pragma unroll
        for (int q = 0; q < 4; ++q) xs[q] = p[(size_t)(s0 + q) * Hc];
#pragma unroll
        for (int q = 0; q < 4; ++q) {
            const float reset = (mem > 1.0f) ? 1.0f : 0.0f;
            float t1 = 0.9f * mem;
            asm volatile("" : "+v"(t1));           // block FMA contraction: match np rounding
            float t2 = t1 + xs[q];
            asm volatile("" : "+v"(t2));
            mem = t2 - reset;                       // reset*THR with THR=1
            o[(size_t)(s0 + q) * CH] = __float2bfloat16((mem > 1.0f) ? 1.0f : 0.0f);
        }
    }
}

// ---------------- conv weight re-layout: w2[o][k*256+i] = cw[o][i][k] ----------------
__global__ __launch_bounds__(256) void k_w2(const float* __restrict__ cw, float* __restrict__ w2) {
    const int idx = blockIdx.x * 256 + threadIdx.x;   // < 196608
    const int o = idx / 768, rem = idx % 768;
    const int k = rem >> 8, i = rem & 255;
    w2[idx] = cw[(size_t)o * 768 + i * 3 + k];
}

// ---------------- halo-expanded conv input: ae[row][k*256+i] = plan[b, s+k-1, i] ----------------
__global__ __launch_bounds__(256) void k_aext(const float* __restrict__ plan, float* __restrict__ ae) {
    const int row = blockIdx.x;
    const int t = threadIdx.x;
    const int b = row >> 9, s = row & 511;
#pragma unroll
    for (int k = 0; k < 3; ++k) {
        const int ss = s + k - 1;
        const float v = (ss >= 0 && ss < Sc) ? plan[(size_t)(b * Sc + ss) * Hc + t] : 0.0f;
        ae[(size_t)row * 768 + k * 256 + t] = v;
    }
}

// ---------------- pack ling + plan into combined (bf16) ----------------
__global__ __launch_bounds__(256) void k_pack(const float* __restrict__ ling,
                                              const float* __restrict__ plan,
                                              __hip_bfloat16* __restrict__ comb) {
    const size_t row = blockIdx.x;
    const int t = threadIdx.x;
    comb[row * CH + 512 + t] = __float2bfloat16(ling[row * Hc + t]);
    comb[row * CH + 768 + t] = __float2bfloat16(plan[row * Hc + t]);
}

// ---------------- head_w fp32 -> bf16 ----------------
__global__ __launch_bounds__(256) void k_cvt_hw(const float* __restrict__ hw,
                                                __hip_bfloat16* __restrict__ hb) {
    const size_t i = (size_t)blockIdx.x * 256 + threadIdx.x;
    hb[i] = __float2bfloat16(hw[i]);
}

// ---------------- head GEMM: logits = combined(bf16) @ head_w(bf16)^T + head_b, fp32 out ----------------
// m97-style: 128x128 tile, BK=32, 4 waves, mfma_f32_16x16x32_bf16, global_load_lds(16B)
__global__ __launch_bounds__(256) void k_head(const __hip_bfloat16* __restrict__ Abf,
                                              const __hip_bfloat16* __restrict__ Bbf,
                                              const float* __restrict__ bias,
                                              float* __restrict__ C) {
    __shared__ __hip_bfloat16 As[128 * 32];
    __shared__ __hip_bfloat16 Bs[128 * 32];
    const int t = threadIdx.x;
    const int tm = blockIdx.x * 128, tn = blockIdx.y * 128;
    const int w = t >> 6, l = t & 63;
    const int wr = w >> 1, wc = w & 1;
    f32x4v acc[4][4];
    const f32x4v zero = {0.f, 0.f, 0.f, 0.f};
#pragma unroll
    for (int i = 0; i < 4; ++i)
#pragma unroll
        for (int j = 0; j < 4; ++j) acc[i][j] = zero;

    for (int kt = 0; kt < CH; kt += 32) {
#pragma unroll
        for (int j = 0; j < 2; ++j) {
            const int c = j * 256 + t;
            const int row = c >> 2, kc = c & 3;
            const __hip_bfloat16* ga = Abf + (size_t)(tm + row) * CH + kt + kc * 8;
            int nrow = tn + row;
            if (nrow > Vc - 1) nrow = Vc - 1;
            const __hip_bfloat16* gb = Bbf + (size_t)nrow * CH + kt + kc * 8;
            __builtin_amdgcn_global_load_lds((const __attribute__((address_space(1))) void*)ga,
                                             (__attribute__((address_space(3))) void*)(As + c * 8),
                                             16, 0, 0);
            __builtin_amdgcn_global_load_lds((const __attribute__((address_space(1))) void*)gb,
                                             (__attribute__((address_space(3))) void*)(Bs + c * 8),
                                             16, 0, 0);
        }
        __syncthreads();
        const int lr = l & 15, lk = (l >> 4) * 8;
        short8v af[4], bf[4];
#pragma unroll
        for (int m = 0; m < 4; ++m)
            af[m] = *(const short8v*)(As + (wr * 64 + m * 16 + lr) * 32 + lk);
#pragma unroll
        for (int n = 0; n < 4; ++n)
            bf[n] = *(const short8v*)(Bs + (wc * 64 + n * 16 + lr) * 32 + lk);
#pragma unroll
        for (int m = 0; m < 4; ++m)
#pragma unroll
            for (int n = 0; n < 4; ++n)
                acc[m][n] = __builtin_amdgcn_mfma_f32_16x16x32_bf16(af[m], bf[n], acc[m][n], 0, 0, 0);
        __syncthreads();
    }
    const int lr = l & 15, lq = (l >> 4) * 4;
#pragma unroll
    for (int n = 0; n < 4; ++n) {
        const int col = tn + wc * 64 + n * 16 + lr;
        if (col >= Vc) continue;
        const float bv = bias[col];
#pragma unroll
        for (int m = 0; m < 4; ++m) {
            const int rbase = tm + wr * 64 + m * 16 + lq;
#pragma unroll
            for (int j = 0; j < 4; ++j)
                C[(size_t)(rbase + j) * Vc + col] = acc[m][n][j] + bv;
        }
    }
}

// ---------------- plan mean over S ----------------
__global__ __launch_bounds__(256) void k_pmean(const float* __restrict__ plan, float* __restrict__ pm) {
    const int b = blockIdx.x;
    const int h = threadIdx.x;
    const float* p = plan + (size_t)b * Sc * Hc + h;
    float s = 0.0f;
    for (int i = 0; i < Sc; ++i) s += p[(size_t)i * Hc];
    pm[b * Hc + h] = s * (1.0f / 512.0f);
}

// ---------------- read softmax + memory read ----------------
__global__ __launch_bounds__(256) void k_memread(const float* __restrict__ pm,
                                                 const float* __restrict__ rw,
                                                 const float* __restrict__ rb,
                                                 const float* __restrict__ memm,
                                                 float* __restrict__ out) {
    const int b = blockIdx.x;
    const int t = threadIdx.x;
    __shared__ float lg[64];
    __shared__ float sm[64];
    if (t < 64) {
        float s = rb[t];
        const float* wrow = rw + (size_t)t * Hc;
        const float* p = pm + (size_t)b * Hc;
        for (int i = 0; i < Hc; ++i) s = fmaf(wrow[i], p[i], s);
        lg[t] = s;
    }
    __syncthreads();
    if (t == 0) {
        float mx = lg[0];
        for (int i = 1; i < 64; ++i) mx = fmaxf(mx, lg[i]);
        float ssum = 0.0f;
        for (int i = 0; i < 64; ++i) { const float e = expf(lg[i] - mx); sm[i] = e; ssum += e; }
        for (int i = 0; i < 64; ++i) sm[i] /= ssum;
    }
    __syncthreads();
    float s = 0.0f;
    for (int m = 0; m < 64; ++m) s = fmaf(sm[m], memm[(size_t)m * Hc + t], s);
    out[(size_t)b * Hc + t] = s;
}

extern "C" void kernel_launch(void* const* d_in, const int* in_sizes, int n_in,
                              void* d_out, int out_size, void* d_ws, size_t ws_size,
                              hipStream_t stream) {
    const int*   ids    = (const int*)  d_in[0];
    const float* embed  = (const float*)d_in[1];
    const float* pos    = (const float*)d_in[2];
    const float* qkv_w  = (const float*)d_in[3];
    const float* qkv_b  = (const float*)d_in[4];
    const float* out_w  = (const float*)d_in[5];
    const float* out_b  = (const float*)d_in[6];
    const float* ln1_g  = (const float*)d_in[7];
    const float* ln1_b  = (const float*)d_in[8];
    const float* ff1_w  = (const float*)d_in[9];
    const float* ff1_b  = (const float*)d_in[10];
    const float* ff2_w  = (const float*)d_in[11];
    const float* ff2_b  = (const float*)d_in[12];
    const float* ln2_g  = (const float*)d_in[13];
    const float* ln2_b  = (const float*)d_in[14];
    const float* log_w  = (const float*)d_in[15];
    const float* log_b  = (const float*)d_in[16];
    const float* mat_w  = (const float*)d_in[17];
    const float* mat_b  = (const float*)d_in[18];
    const float* conv_w = (const float*)d_in[19];
    const float* conv_b = (const float*)d_in[20];
    const float* read_w = (const float*)d_in[21];
    const float* read_b = (const float*)d_in[22];
    const float* memory = (const float*)d_in[23];
    const float* head_w = (const float*)d_in[24];
    const float* head_b = (const float*)d_in[25];

    char* wsb = (char*)d_ws;
    float* X   = (float*)(wsb + 0);                    //  8 MB  [8192,256]
    float* RES = (float*)(wsb + 8388608);              //  8 MB  [8192,256]
    float* QKV = (float*)(wsb + 16777216);             // 24 MB  [8192,768] (later h1, A_ext)
    float* ATT = (float*)(wsb + 41943040);             // 64 MB  [64,512,512] (later proj_log/mat)
    float* O   = (float*)(wsb + 109051904);            //  8 MB  [8192,256] (later ling)
    __hip_bfloat16* COMB = (__hip_bfloat16*)(wsb + 117440512);  // 16 MB [8192,1024]
    __hip_bfloat16* HWB  = (__hip_bfloat16*)(wsb + 134217728);  // 16 MB [8000,1024]
    float* W2  = (float*)(wsb + 150601728);            // 768 KB [256,768]
    float* PLOG = ATT;
    float* PMAT = ATT + 2097152;
    float* AEXT = QKV;
    float* PM   = RES;
    float* logits = (float*)d_out;
    float* mread  = logits + (size_t)ROWS * Vc;

    k_embed<<<dim3(ROWS), dim3(256), 0, stream>>>(ids, embed, pos, X);
    for (int l = 0; l < 2; ++l) {
        // qkv: [8192,256] @ [768,256]^T -> [8192,768]
        k_gemm128<0><<<dim3(64, 6, 1), 256, 0, stream>>>(X, qkv_w + (size_t)l * 768 * 256,
                                                         qkv_b + l * 768, QKV,
                                                         256, 256, 256, 768, 0, 0, 0, 0, 0, 0);
        // scores: per z=(b,h): Q[512,64] @ K[512,64]^T * 0.125 -> att[z]
        k_gemm128<2><<<dim3(4, 4, 64), 256, 0, stream>>>(QKV, QKV + 256, nullptr, ATT,
                                                         64, 768, 768, 512,
                                                         (long)512 * 768, 64,
                                                         (long)512 * 768, 64,
                                                         (long)4 * 512 * 512, (long)512 * 512);
        k_softmax<<<dim3(32768), 256, 0, stream>>>(ATT);
        k_av128<<<dim3(4, 64), 256, 0, stream>>>(ATT, QKV, O);
        // out proj: [8192,256] @ [256,256]^T -> RES
        k_gemm128<0><<<dim3(64, 2, 1), 256, 0, stream>>>(O, out_w + (size_t)l * 256 * 256,
                                                         out_b + l * 256, RES,
                                                         256, 256, 256, 256, 0, 0, 0, 0, 0, 0);
        k_add_ln<<<dim3(ROWS), 256, 0, stream>>>(X, RES, ln1_g + l * 256, ln1_b + l * 256);
        // ff1 + gelu: [8192,256] @ [512,256]^T -> QKV(h1)
        k_gemm128<1><<<dim3(64, 4, 1), 256, 0, stream>>>(X, ff1_w + (size_t)l * 512 * 256,
                                                         ff1_b + l * 512, QKV,
                                                         256, 256, 256, 512, 0, 0, 0, 0, 0, 0);
        // ff2: [8192,512] @ [256,512]^T -> RES
        k_gemm128<0><<<dim3(64, 2, 1), 256, 0, stream>>>(QKV, ff2_w + (size_t)l * 256 * 512,
                                                         ff2_b + l * 256, RES,
                                                         512, 512, 512, 256, 0, 0, 0, 0, 0, 0);
        k_add_ln<<<dim3(ROWS), 256, 0, stream>>>(X, RES, ln2_g + l * 256, ln2_b + l * 256);
    }
    // plan = X
    k_gemm128<0><<<dim3(64, 2, 1), 256, 0, stream>>>(X, log_w, log_b, PLOG,
                                                     256, 256, 256, 256, 0, 0, 0, 0, 0, 0);
    k_gemm128<0><<<dim3(64, 2, 1), 256, 0, stream>>>(X, mat_w, mat_b, PMAT,
                                                     256, 256, 256, 256, 0, 0, 0, 0, 0, 0);
    k_lif<<<dim3(Bc), 256, 0, stream>>>(PLOG, COMB, 0);
    k_lif<<<dim3(Bc), 256, 0, stream>>>(PMAT, COMB, 256);
    k_w2<<<dim3(768), 256, 0, stream>>>(conv_w, W2);
    k_aext<<<dim3(ROWS), 256, 0, stream>>>(X, AEXT);
    // conv as GEMM: [8192,768] @ [256,768]^T -> O(ling)
    k_gemm128<0><<<dim3(64, 2, 1), 256, 0, stream>>>(AEXT, W2, conv_b, O,
                                                     768, 768, 768, 256, 0, 0, 0, 0, 0, 0);
    k_pack<<<dim3(ROWS), 256, 0, stream>>>(O, X, COMB);
    k_cvt_hw<<<dim3(32000), 256, 0, stream>>>(head_w, HWB);
    k_head<<<dim3(64, 63), 256, 0, stream>>>(COMB, HWB, head_b, logits);
    k_pmean<<<dim3(Bc), 256, 0, stream>>>(X, PM);
    k_memread<<<dim3(Bc), 256, 0, stream>>>(PM, read_w, read_b, memory, mread);
}

// Round 3
// 998.841 us; speedup vs baseline: 1.2140x; 1.2140x over previous
//
#include <hip/hip_runtime.h>
#include <hip/hip_bf16.h>

// Problem constants
constexpr int Bc = 16, Sc = 512, Hc = 256, Vc = 8000, NHc = 4, HDc = 64;
constexpr int FFc = 512, Mc = 64;
constexpr int ROWS = Bc * Sc;      // 8192
constexpr int CH = 4 * Hc;         // 1024

typedef __attribute__((ext_vector_type(4))) float f32x4v;
typedef __attribute__((ext_vector_type(8))) short short8v;
typedef __hip_bfloat16 bf16;

// ---- 3-way bf16 split: x = h + m + l + O(2^-27 |x|) ----
__device__ inline void split3(float x, bf16& h, bf16& m, bf16& l) {
    h = __float2bfloat16(x);
    const float r = x - __bfloat162float(h);   // exact (Sterbenz)
    m = __float2bfloat16(r);
    const float r2 = r - __bfloat162float(m);  // exact
    l = __float2bfloat16(r2);
}

// ---------------- embed + pos (+ split planes) ----------------
__global__ __launch_bounds__(256) void k_embed(const int* __restrict__ ids,
                                               const float* __restrict__ emb,
                                               const float* __restrict__ pos,
                                               float* __restrict__ x,
                                               bf16* __restrict__ xh, bf16* __restrict__ xm,
                                               bf16* __restrict__ xl) {
    const int r = blockIdx.x;          // 0..8191
    const int h = threadIdx.x;         // 0..255
    const int s = r & (Sc - 1);
    const int id = ids[r];
    const float v = emb[(size_t)id * Hc + h] + pos[(size_t)s * Hc + h];
    const size_t o = (size_t)r * Hc + h;
    x[o] = v;
    split3(v, xh[o], xm[o], xl[o]);
}

// ---------------- generic fp32 -> 3-plane split (4 elems/thread) ----------------
__global__ __launch_bounds__(256) void k_split3(const float* __restrict__ in,
                                                bf16* __restrict__ h, bf16* __restrict__ m,
                                                bf16* __restrict__ l) {
    const size_t i = ((size_t)blockIdx.x * 256 + threadIdx.x) * 4;
    const float4 v = *(const float4*)&in[i];
    split3(v.x, h[i + 0], m[i + 0], l[i + 0]);
    split3(v.y, h[i + 1], m[i + 1], l[i + 1]);
    split3(v.z, h[i + 2], m[i + 2], l[i + 2]);
    split3(v.w, h[i + 3], m[i + 3], l[i + 3]);
}

// ---------------- bf16x3 MFMA GEMM: C = A[M,K] @ B[N,K]^T (+bias, gelu, split-out) ----------------
// EPI: 0 = +bias, 1 = gelu(x+bias).  OUTS: 0 = fp32 C, 1 = split3 planes Oh/Om/Ol.
// 128x128 tile, BK=32, 4 waves (2x2 of 64x64), mfma_f32_16x16x32_bf16, global_load_lds(16B).
template <int EPI, int OUTS>
__global__ __launch_bounds__(256) void k_mfma3(const bf16* __restrict__ Ah,
                                               const bf16* __restrict__ Am,
                                               const bf16* __restrict__ Al,
                                               const bf16* __restrict__ Bh,
                                               const bf16* __restrict__ Bm,
                                               const bf16* __restrict__ Bl,
                                               const float* __restrict__ bias,
                                               float* __restrict__ C,
                                               bf16* __restrict__ Oh, bf16* __restrict__ Om,
                                               bf16* __restrict__ Ol,
                                               int K, int N) {
    __shared__ bf16 As[3][128 * 32];
    __shared__ bf16 Bs[3][128 * 32];
    const int t = threadIdx.x;
    const int tm = blockIdx.x * 128, tn = blockIdx.y * 128;
    const int w = t >> 6, l = t & 63;
    const int wr = w >> 1, wc = w & 1;
    f32x4v acc[4][4];
    const f32x4v zero = {0.f, 0.f, 0.f, 0.f};
#pragma unroll
    for (int i = 0; i < 4; ++i)
#pragma unroll
        for (int j = 0; j < 4; ++j) acc[i][j] = zero;

    const bf16* Ap[3] = {Ah, Am, Al};
    const bf16* Bp[3] = {Bh, Bm, Bl};

    for (int kt = 0; kt < K; kt += 32) {
#pragma unroll
        for (int p = 0; p < 3; ++p) {
#pragma unroll
            for (int j = 0; j < 2; ++j) {
                const int c = j * 256 + t;
                const int row = c >> 2, kc = c & 3;
                const bf16* ga = Ap[p] + (size_t)(tm + row) * K + kt + kc * 8;
                const bf16* gb = Bp[p] + (size_t)(tn + row) * K + kt + kc * 8;
                __builtin_amdgcn_global_load_lds((const __attribute__((address_space(1))) void*)ga,
                                                 (__attribute__((address_space(3))) void*)(&As[p][0] + c * 8),
                                                 16, 0, 0);
                __builtin_amdgcn_global_load_lds((const __attribute__((address_space(1))) void*)gb,
                                                 (__attribute__((address_space(3))) void*)(&Bs[p][0] + c * 8),
                                                 16, 0, 0);
            }
        }
        __syncthreads();
        const int lr = l & 15, lk = (l >> 4) * 8;
        short8v af[3][4], bf[3][4];
#pragma unroll
        for (int p = 0; p < 3; ++p)
#pragma unroll
            for (int m = 0; m < 4; ++m)
                af[p][m] = *(const short8v*)(&As[p][0] + (wr * 64 + m * 16 + lr) * 32 + lk);
#pragma unroll
        for (int p = 0; p < 3; ++p)
#pragma unroll
            for (int n = 0; n < 4; ++n)
                bf[p][n] = *(const short8v*)(&Bs[p][0] + (wc * 64 + n * 16 + lr) * 32 + lk);
        // 6 term passes: hh, hm, mh, hl, lh, mm — each 16 independent MFMAs
#pragma unroll
        for (int m = 0; m < 4; ++m)
#pragma unroll
            for (int n = 0; n < 4; ++n)
                acc[m][n] = __builtin_amdgcn_mfma_f32_16x16x32_bf16(af[0][m], bf[0][n], acc[m][n], 0, 0, 0);
#pragma unroll
        for (int m = 0; m < 4; ++m)
#pragma unroll
            for (int n = 0; n < 4; ++n)
                acc[m][n] = __builtin_amdgcn_mfma_f32_16x16x32_bf16(af[0][m], bf[1][n], acc[m][n], 0, 0, 0);
#pragma unroll
        for (int m = 0; m < 4; ++m)
#pragma unroll
            for (int n = 0; n < 4; ++n)
                acc[m][n] = __builtin_amdgcn_mfma_f32_16x16x32_bf16(af[1][m], bf[0][n], acc[m][n], 0, 0, 0);
#pragma unroll
        for (int m = 0; m < 4; ++m)
#pragma unroll
            for (int n = 0; n < 4; ++n)
                acc[m][n] = __builtin_amdgcn_mfma_f32_16x16x32_bf16(af[0][m], bf[2][n], acc[m][n], 0, 0, 0);
#pragma unroll
        for (int m = 0; m < 4; ++m)
#pragma unroll
            for (int n = 0; n < 4; ++n)
                acc[m][n] = __builtin_amdgcn_mfma_f32_16x16x32_bf16(af[2][m], bf[0][n], acc[m][n], 0, 0, 0);
#pragma unroll
        for (int m = 0; m < 4; ++m)
#pragma unroll
            for (int n = 0; n < 4; ++n)
                acc[m][n] = __builtin_amdgcn_mfma_f32_16x16x32_bf16(af[1][m], bf[1][n], acc[m][n], 0, 0, 0);
        __syncthreads();
    }
    const int lr = l & 15, lq = (l >> 4) * 4;
#pragma unroll
    for (int n = 0; n < 4; ++n) {
        const int col = tn + wc * 64 + n * 16 + lr;
        const float bv = bias[col];
#pragma unroll
        for (int m = 0; m < 4; ++m) {
            const int rbase = tm + wr * 64 + m * 16 + lq;
#pragma unroll
            for (int j = 0; j < 4; ++j) {
                float v = acc[m][n][j] + bv;
                if (EPI == 1) v = 0.5f * v * (1.0f + erff(v / 1.41421356237309515f));
                const size_t o = (size_t)(rbase + j) * N + col;
                if (OUTS == 0) {
                    C[o] = v;
                } else {
                    split3(v, Oh[o], Om[o], Ol[o]);
                }
            }
        }
    }
}

// ---------------- attention scores (fp32): att[z,q,k] = (q.k)/8, batched 128x128 ----------------
template <int EPI>
__global__ __launch_bounds__(256) void k_gemm128(const float* __restrict__ A,
                                                 const float* __restrict__ Bm,
                                                 float* __restrict__ C,
                                                 int K, int lda, int ldb, int ldc,
                                                 long zAh, long zAl, long zBh, long zBl,
                                                 long zCh, long zCl) {
    __shared__ float As[16][132];
    __shared__ float Bs[16][132];
    const int z = blockIdx.z;
    const int z4 = z >> 2, zl = z & 3;
    A  += (size_t)z4 * zAh + (size_t)zl * zAl;
    Bm += (size_t)z4 * zBh + (size_t)zl * zBl;
    C  += (size_t)z4 * zCh + (size_t)zl * zCl;
    const int t = threadIdx.x;
    const int tm = blockIdx.x * 128, tn = blockIdx.y * 128;
    const int tx = t & 15, ty = t >> 4;
    float acc[8][8] = {};
    for (int kt = 0; kt < K; kt += 16) {
#pragma unroll
        for (int q = 0; q < 2; ++q) {
            const int f = t + q * 256;          // 0..511
            const int row = f >> 2, kc = (f & 3) * 4;
            const float4 av = *(const float4*)&A[(size_t)(tm + row) * lda + kt + kc];
            const float4 bv = *(const float4*)&Bm[(size_t)(tn + row) * ldb + kt + kc];
            As[kc + 0][row] = av.x; As[kc + 1][row] = av.y;
            As[kc + 2][row] = av.z; As[kc + 3][row] = av.w;
            const int sr = (row & 15) * 8 + (row >> 4);   // interleaved B layout
            Bs[kc + 0][sr] = bv.x; Bs[kc + 1][sr] = bv.y;
            Bs[kc + 2][sr] = bv.z; Bs[kc + 3][sr] = bv.w;
        }
        __syncthreads();
#pragma unroll
        for (int kk = 0; kk < 16; ++kk) {
            float a8[8], b8[8];
            *(float4*)&a8[0] = *(const float4*)&As[kk][ty * 8];
            *(float4*)&a8[4] = *(const float4*)&As[kk][ty * 8 + 4];
            *(float4*)&b8[0] = *(const float4*)&Bs[kk][tx * 8];
            *(float4*)&b8[4] = *(const float4*)&Bs[kk][tx * 8 + 4];
#pragma unroll
            for (int i = 0; i < 8; ++i)
#pragma unroll
                for (int j = 0; j < 8; ++j)
                    acc[i][j] = fmaf(a8[i], b8[j], acc[i][j]);
        }
        __syncthreads();
    }
#pragma unroll
    for (int i = 0; i < 8; ++i) {
        const size_t r = tm + ty * 8 + i;
#pragma unroll
        for (int j = 0; j < 8; ++j) {
            const int c = tn + j * 16 + tx;
            float v = acc[i][j];
            if (EPI == 2) v *= 0.125f;
            C[r * ldc + c] = v;
        }
    }
}

// ---------------- softmax over 512-wide rows ----------------
__global__ __launch_bounds__(256) void k_softmax(float* __restrict__ att) {
    float* p = att + (size_t)blockIdx.x * Sc;
    const int t = threadIdx.x;
    float v0 = p[t], v1 = p[t + 256];
    __shared__ float red[256];
    red[t] = fmaxf(v0, v1);
    __syncthreads();
    for (int s = 128; s > 0; s >>= 1) { if (t < s) red[t] = fmaxf(red[t], red[t + s]); __syncthreads(); }
    const float mx = red[0];
    __syncthreads();
    const float e0 = expf(v0 - mx), e1 = expf(v1 - mx);
    red[t] = e0 + e1;
    __syncthreads();
    for (int s = 128; s > 0; s >>= 1) { if (t < s) red[t] += red[t + s]; __syncthreads(); }
    const float sum = red[0];
    p[t] = e0 / sum;
    p[t + 256] = e1 / sum;
}

// ---------------- O = att @ V (fp32), split3 epilogue to planes ----------------
__global__ __launch_bounds__(256) void k_av128(const float* __restrict__ att,
                                               const float* __restrict__ qkv,
                                               bf16* __restrict__ Oh, bf16* __restrict__ Om,
                                               bf16* __restrict__ Ol) {
    const int z = blockIdx.y;
    const int b = z >> 2, h = z & 3;
    const float* ab = att + (size_t)z * Sc * Sc;
    const float* vb = qkv + (size_t)b * Sc * (3 * Hc) + 2 * Hc + h * HDc;
    const int tm = blockIdx.x * 128;
    __shared__ float As[16][132];
    __shared__ float Vs[16][68];
    const int t = threadIdx.x, tx = t & 15, ty = t >> 4;
    float acc[8][4] = {};
    for (int kt = 0; kt < Sc; kt += 16) {
#pragma unroll
        for (int q = 0; q < 2; ++q) {
            const int f = t + q * 256;
            const int row = f >> 2, kc = (f & 3) * 4;
            const float4 av = *(const float4*)&ab[(size_t)(tm + row) * Sc + kt + kc];
            As[kc + 0][row] = av.x; As[kc + 1][row] = av.y;
            As[kc + 2][row] = av.z; As[kc + 3][row] = av.w;
        }
#pragma unroll
        for (int q = 0; q < 4; ++q) {
            const int f = t + q * 256;          // 0..1023
            const int kk = f >> 6, c = f & 63;
            Vs[kk][c] = vb[(size_t)(kt + kk) * (3 * Hc) + c];
        }
        __syncthreads();
#pragma unroll
        for (int kk = 0; kk < 16; ++kk) {
            float a8[8];
            *(float4*)&a8[0] = *(const float4*)&As[kk][ty * 8];
            *(float4*)&a8[4] = *(const float4*)&As[kk][ty * 8 + 4];
            float b4[4];
#pragma unroll
            for (int j = 0; j < 4; ++j) b4[j] = Vs[kk][tx + j * 16];
#pragma unroll
            for (int i = 0; i < 8; ++i)
#pragma unroll
                for (int j = 0; j < 4; ++j)
                    acc[i][j] = fmaf(a8[i], b4[j], acc[i][j]);
        }
        __syncthreads();
    }
#pragma unroll
    for (int i = 0; i < 8; ++i)
#pragma unroll
        for (int j = 0; j < 4; ++j) {
            const size_t o = (size_t)(b * Sc + tm + ty * 8 + i) * Hc + h * HDc + tx + j * 16;
            split3(acc[i][j], Oh[o], Om[o], Ol[o]);
        }
}

// ---------------- x = LayerNorm(x + res) * g + b (+ split planes) ----------------
__global__ __launch_bounds__(256) void k_add_ln(float* __restrict__ x,
                                                const float* __restrict__ res,
                                                const float* __restrict__ g,
                                                const float* __restrict__ b,
                                                bf16* __restrict__ xh, bf16* __restrict__ xm,
                                                bf16* __restrict__ xl) {
    const size_t row = blockIdx.x;
    const int t = threadIdx.x;
    float v = x[row * Hc + t] + res[row * Hc + t];
    __shared__ float red[256];
    red[t] = v;
    __syncthreads();
    for (int s = 128; s > 0; s >>= 1) { if (t < s) red[t] += red[t + s]; __syncthreads(); }
    const float mean = red[0] * (1.0f / 256.0f);
    __syncthreads();
    const float d = v - mean;
    red[t] = d * d;
    __syncthreads();
    for (int s = 128; s > 0; s >>= 1) { if (t < s) red[t] += red[t + s]; __syncthreads(); }
    const float var = red[0] * (1.0f / 256.0f);
    const float out = d / sqrtf(var + 1e-5f) * g[t] + b[t];
    const size_t o = row * Hc + t;
    x[o] = out;
    split3(out, xh[o], xm[o], xl[o]);
}

// ---------------- LIF scan; writes 0/1 spikes (bf16-exact) into combined ----------------
__global__ __launch_bounds__(256) void k_lif(const float* __restrict__ proj,
                                             bf16* __restrict__ comb,
                                             int colOff) {
    const int b = blockIdx.x;
    const int h = threadIdx.x;
    const float* p = proj + (size_t)b * Sc * Hc + h;
    bf16* o = comb + (size_t)b * Sc * CH + colOff + h;
    float mem = 0.0f;
    for (int s0 = 0; s0 < Sc; s0 += 4) {
        float xs[4];
#pragma unroll
        for (int q = 0; q < 4; ++q) xs[q] = p[(size_t)(s0 + q) * Hc];
#pragma unroll
        for (int q = 0; q < 4; ++q) {
            const float reset = (mem > 1.0f) ? 1.0f : 0.0f;
            float t1 = 0.9f * mem;
            asm volatile("" : "+v"(t1));           // block FMA contraction: match np rounding
            float t2 = t1 + xs[q];
            asm volatile("" : "+v"(t2));
            mem = t2 - reset;                       // reset*THR with THR=1
            o[(size_t)(s0 + q) * CH] = __float2bfloat16((mem > 1.0f) ? 1.0f : 0.0f);
        }
    }
}

// ---------------- conv weight re-layout + split: w2p[o][k*256+i] = split(cw[o][i][k]) ----------------
__global__ __launch_bounds__(256) void k_w2s(const float* __restrict__ cw,
                                             bf16* __restrict__ wh, bf16* __restrict__ wm,
                                             bf16* __restrict__ wl) {
    const int idx = blockIdx.x * 256 + threadIdx.x;   // < 196608
    const int o = idx / 768, rem = idx % 768;
    const int k = rem >> 8, i = rem & 255;
    split3(cw[(size_t)o * 768 + i * 3 + k], wh[idx], wm[idx], wl[idx]);
}

// ---------------- halo-expanded conv input planes: ae[row][k*256+i] = xplane[b, s+k-1, i] ----------------
__global__ __launch_bounds__(256) void k_aext3(const bf16* __restrict__ xh,
                                               const bf16* __restrict__ xm,
                                               const bf16* __restrict__ xl,
                                               bf16* __restrict__ aeh, bf16* __restrict__ aem,
                                               bf16* __restrict__ ael) {
    const int row = blockIdx.x;
    const int t = threadIdx.x;
    const int b = row >> 9, s = row & 511;
    const bf16 z = __float2bfloat16(0.0f);
#pragma unroll
    for (int k = 0; k < 3; ++k) {
        const int ss = s + k - 1;
        const size_t dst = (size_t)row * 768 + k * 256 + t;
        if (ss >= 0 && ss < Sc) {
            const size_t src = (size_t)(b * Sc + ss) * Hc + t;
            aeh[dst] = xh[src]; aem[dst] = xm[src]; ael[dst] = xl[src];
        } else {
            aeh[dst] = z; aem[dst] = z; ael[dst] = z;
        }
    }
}

// ---------------- pack ling + plan into combined (bf16) ----------------
__global__ __launch_bounds__(256) void k_pack(const float* __restrict__ ling,
                                              const float* __restrict__ plan,
                                              bf16* __restrict__ comb) {
    const size_t row = blockIdx.x;
    const int t = threadIdx.x;
    comb[row * CH + 512 + t] = __float2bfloat16(ling[row * Hc + t]);
    comb[row * CH + 768 + t] = __float2bfloat16(plan[row * Hc + t]);
}

// ---------------- head_w fp32 -> bf16 (4/thread) ----------------
__global__ __launch_bounds__(256) void k_cvt_hw(const float* __restrict__ hw,
                                                bf16* __restrict__ hb) {
    const size_t i = ((size_t)blockIdx.x * 256 + threadIdx.x) * 4;
    const float4 v = *(const float4*)&hw[i];
    hb[i + 0] = __float2bfloat16(v.x);
    hb[i + 1] = __float2bfloat16(v.y);
    hb[i + 2] = __float2bfloat16(v.z);
    hb[i + 3] = __float2bfloat16(v.w);
}

// ---------------- head GEMM: logits = combined(bf16) @ head_w(bf16)^T + head_b, fp32 out ----------------
__global__ __launch_bounds__(256) void k_head(const bf16* __restrict__ Abf,
                                              const bf16* __restrict__ Bbf,
                                              const float* __restrict__ bias,
                                              float* __restrict__ C) {
    __shared__ bf16 As[128 * 32];
    __shared__ bf16 Bs[128 * 32];
    const int t = threadIdx.x;
    const int tm = blockIdx.x * 128, tn = blockIdx.y * 128;
    const int w = t >> 6, l = t & 63;
    const int wr = w >> 1, wc = w & 1;
    f32x4v acc[4][4];
    const f32x4v zero = {0.f, 0.f, 0.f, 0.f};
#pragma unroll
    for (int i = 0; i < 4; ++i)
#pragma unroll
        for (int j = 0; j < 4; ++j) acc[i][j] = zero;

    for (int kt = 0; kt < CH; kt += 32) {
#pragma unroll
        for (int j = 0; j < 2; ++j) {
            const int c = j * 256 + t;
            const int row = c >> 2, kc = c & 3;
            const bf16* ga = Abf + (size_t)(tm + row) * CH + kt + kc * 8;
            int nrow = tn + row;
            if (nrow > Vc - 1) nrow = Vc - 1;
            const bf16* gb = Bbf + (size_t)nrow * CH + kt + kc * 8;
            __builtin_amdgcn_global_load_lds((const __attribute__((address_space(1))) void*)ga,
                                             (__attribute__((address_space(3))) void*)(As + c * 8),
                                             16, 0, 0);
            __builtin_amdgcn_global_load_lds((const __attribute__((address_space(1))) void*)gb,
                                             (__attribute__((address_space(3))) void*)(Bs + c * 8),
                                             16, 0, 0);
        }
        __syncthreads();
        const int lr = l & 15, lk = (l >> 4) * 8;
        short8v af[4], bf[4];
#pragma unroll
        for (int m = 0; m < 4; ++m)
            af[m] = *(const short8v*)(As + (wr * 64 + m * 16 + lr) * 32 + lk);
#pragma unroll
        for (int n = 0; n < 4; ++n)
            bf[n] = *(const short8v*)(Bs + (wc * 64 + n * 16 + lr) * 32 + lk);
#pragma unroll
        for (int m = 0; m < 4; ++m)
#pragma unroll
            for (int n = 0; n < 4; ++n)
                acc[m][n] = __builtin_amdgcn_mfma_f32_16x16x32_bf16(af[m], bf[n], acc[m][n], 0, 0, 0);
        __syncthreads();
    }
    const int lr = l & 15, lq = (l >> 4) * 4;
#pragma unroll
    for (int n = 0; n < 4; ++n) {
        const int col = tn + wc * 64 + n * 16 + lr;
        if (col >= Vc) continue;
        const float bv = bias[col];
#pragma unroll
        for (int m = 0; m < 4; ++m) {
            const int rbase = tm + wr * 64 + m * 16 + lq;
#pragma unroll
            for (int j = 0; j < 4; ++j)
                C[(size_t)(rbase + j) * Vc + col] = acc[m][n][j] + bv;
        }
    }
}

// ---------------- plan mean over S ----------------
__global__ __launch_bounds__(256) void k_pmean(const float* __restrict__ plan, float* __restrict__ pm) {
    const int b = blockIdx.x;
    const int h = threadIdx.x;
    const float* p = plan + (size_t)b * Sc * Hc + h;
    float s = 0.0f;
    for (int i = 0; i < Sc; ++i) s += p[(size_t)i * Hc];
    pm[b * Hc + h] = s * (1.0f / 512.0f);
}

// ---------------- read softmax + memory read ----------------
__global__ __launch_bounds__(256) void k_memread(const float* __restrict__ pm,
                                                 const float* __restrict__ rw,
                                                 const float* __restrict__ rb,
                                                 const float* __restrict__ memm,
                                                 float* __restrict__ out) {
    const int b = blockIdx.x;
    const int t = threadIdx.x;
    __shared__ float lg[64];
    __shared__ float sm[64];
    if (t < 64) {
        float s = rb[t];
        const float* wrow = rw + (size_t)t * Hc;
        const float* p = pm + (size_t)b * Hc;
        for (int i = 0; i < Hc; ++i) s = fmaf(wrow[i], p[i], s);
        lg[t] = s;
    }
    __syncthreads();
    if (t == 0) {
        float mx = lg[0];
        for (int i = 1; i < 64; ++i) mx = fmaxf(mx, lg[i]);
        float ssum = 0.0f;
        for (int i = 0; i < 64; ++i) { const float e = expf(lg[i] - mx); sm[i] = e; ssum += e; }
        for (int i = 0; i < 64; ++i) sm[i] /= ssum;
    }
    __syncthreads();
    float s = 0.0f;
    for (int m = 0; m < 64; ++m) s = fmaf(sm[m], memm[(size_t)m * Hc + t], s);
    out[(size_t)b * Hc + t] = s;
}

extern "C" void kernel_launch(void* const* d_in, const int* in_sizes, int n_in,
                              void* d_out, int out_size, void* d_ws, size_t ws_size,
                              hipStream_t stream) {
    const int*   ids    = (const int*)  d_in[0];
    const float* embed  = (const float*)d_in[1];
    const float* pos    = (const float*)d_in[2];
    const float* qkv_w  = (const float*)d_in[3];
    const float* qkv_b  = (const float*)d_in[4];
    const float* out_w  = (const float*)d_in[5];
    const float* out_b  = (const float*)d_in[6];
    const float* ln1_g  = (const float*)d_in[7];
    const float* ln1_b  = (const float*)d_in[8];
    const float* ff1_w  = (const float*)d_in[9];
    const float* ff1_b  = (const float*)d_in[10];
    const float* ff2_w  = (const float*)d_in[11];
    const float* ff2_b  = (const float*)d_in[12];
    const float* ln2_g  = (const float*)d_in[13];
    const float* ln2_b  = (const float*)d_in[14];
    const float* log_w  = (const float*)d_in[15];
    const float* log_b  = (const float*)d_in[16];
    const float* mat_w  = (const float*)d_in[17];
    const float* mat_b  = (const float*)d_in[18];
    const float* conv_w = (const float*)d_in[19];
    const float* conv_b = (const float*)d_in[20];
    const float* read_w = (const float*)d_in[21];
    const float* read_b = (const float*)d_in[22];
    const float* memory = (const float*)d_in[23];
    const float* head_w = (const float*)d_in[24];
    const float* head_b = (const float*)d_in[25];

    char* wsb = (char*)d_ws;
    const size_t MB = 1ull << 20;
    float* X    = (float*)(wsb + 0);           // 8 MB [8192,256]
    bf16*  XH   = (bf16*)(wsb + 8 * MB);       // 4 MB
    bf16*  XM   = (bf16*)(wsb + 12 * MB);
    bf16*  XL   = (bf16*)(wsb + 16 * MB);
    float* RES  = (float*)(wsb + 20 * MB);     // 8 MB (also conv "ling" output)
    float* QKV  = (float*)(wsb + 28 * MB);     // 24 MB [8192,768]
    float* ATT  = (float*)(wsb + 52 * MB);     // 64 MB [64,512,512]
    bf16*  H1H  = (bf16*)(wsb + 52 * MB);      // 8 MB each (inside ATT, live only ff1->ff2)
    bf16*  H1M  = (bf16*)(wsb + 60 * MB);
    bf16*  H1L  = (bf16*)(wsb + 68 * MB);
    float* PLOG = (float*)(wsb + 52 * MB);     // 8 MB (post-layers, inside ATT)
    float* PMAT = (float*)(wsb + 60 * MB);     // 8 MB
    bf16*  AEH  = (bf16*)(wsb + 68 * MB);      // 12 MB each (post-layers, inside ATT)
    bf16*  AEM  = (bf16*)(wsb + 80 * MB);
    bf16*  AEL  = (bf16*)(wsb + 92 * MB);
    bf16*  OH   = (bf16*)(wsb + 116 * MB);     // 4 MB each
    bf16*  OM   = (bf16*)(wsb + 120 * MB);
    bf16*  OL   = (bf16*)(wsb + 124 * MB);
    bf16*  COMB = (bf16*)(wsb + 128 * MB);     // 16 MB [8192,1024]
    bf16*  HWB  = (bf16*)(wsb + 144 * MB);     // 16 MB [8000,1024]
    bf16*  WP   = (bf16*)(wsb + 160 * MB);     // weight planes, ~8.3 MB
    float* PM   = QKV;                          // [16,256] reuse (free post-layers)

    // weight plane sub-offsets (elements)
    bf16* qkvwh = WP;             bf16* qkvwm = qkvwh + 393216; bf16* qkvwl = qkvwm + 393216;
    bf16* outwh = qkvwl + 393216; bf16* outwm = outwh + 131072; bf16* outwl = outwm + 131072;
    bf16* ff1wh = outwl + 131072; bf16* ff1wm = ff1wh + 262144; bf16* ff1wl = ff1wm + 262144;
    bf16* ff2wh = ff1wl + 262144; bf16* ff2wm = ff2wh + 262144; bf16* ff2wl = ff2wm + 262144;
    bf16* logwh = ff2wl + 262144; bf16* logwm = logwh + 65536;  bf16* logwl = logwm + 65536;
    bf16* matwh = logwl + 65536;  bf16* matwm = matwh + 65536;  bf16* matwl = matwm + 65536;
    bf16* w2h   = matwl + 65536;  bf16* w2m   = w2h + 196608;   bf16* w2l   = w2m + 196608;

    float* logits = (float*)d_out;
    float* mread  = logits + (size_t)ROWS * Vc;

    // weight splits
    k_split3<<<dim3(384),  256, 0, stream>>>(qkv_w, qkvwh, qkvwm, qkvwl);
    k_split3<<<dim3(128),  256, 0, stream>>>(out_w, outwh, outwm, outwl);
    k_split3<<<dim3(256),  256, 0, stream>>>(ff1_w, ff1wh, ff1wm, ff1wl);
    k_split3<<<dim3(256),  256, 0, stream>>>(ff2_w, ff2wh, ff2wm, ff2wl);
    k_split3<<<dim3(64),   256, 0, stream>>>(log_w, logwh, logwm, logwl);
    k_split3<<<dim3(64),   256, 0, stream>>>(mat_w, matwh, matwm, matwl);
    k_w2s<<<dim3(768),     256, 0, stream>>>(conv_w, w2h, w2m, w2l);
    k_cvt_hw<<<dim3(8000), 256, 0, stream>>>(head_w, HWB);

    k_embed<<<dim3(ROWS), 256, 0, stream>>>(ids, embed, pos, X, XH, XM, XL);
    for (int l = 0; l < 2; ++l) {
        // qkv: [8192,256] x3 @ [768,256]^T x3 -> QKV fp32
        k_mfma3<0, 0><<<dim3(64, 6), 256, 0, stream>>>(
            XH, XM, XL, qkvwh + (size_t)l * 196608, qkvwm + (size_t)l * 196608,
            qkvwl + (size_t)l * 196608, qkv_b + l * 768, QKV, nullptr, nullptr, nullptr, 256, 768);
        // scores (fp32): per z: Q[512,64] @ K[512,64]^T * 0.125
        k_gemm128<2><<<dim3(4, 4, 64), 256, 0, stream>>>(QKV, QKV + 256, ATT,
                                                         64, 768, 768, 512,
                                                         (long)512 * 768, 64,
                                                         (long)512 * 768, 64,
                                                         (long)4 * 512 * 512, (long)512 * 512);
        k_softmax<<<dim3(32768), 256, 0, stream>>>(ATT);
        k_av128<<<dim3(4, 64), 256, 0, stream>>>(ATT, QKV, OH, OM, OL);
        // out proj: O planes @ out_w^T -> RES
        k_mfma3<0, 0><<<dim3(64, 2), 256, 0, stream>>>(
            OH, OM, OL, outwh + (size_t)l * 65536, outwm + (size_t)l * 65536,
            outwl + (size_t)l * 65536, out_b + l * 256, RES, nullptr, nullptr, nullptr, 256, 256);
        k_add_ln<<<dim3(ROWS), 256, 0, stream>>>(X, RES, ln1_g + l * 256, ln1_b + l * 256, XH, XM, XL);
        // ff1 + gelu -> H1 planes
        k_mfma3<1, 1><<<dim3(64, 4), 256, 0, stream>>>(
            XH, XM, XL, ff1wh + (size_t)l * 131072, ff1wm + (size_t)l * 131072,
            ff1wl + (size_t)l * 131072, ff1_b + l * 512, nullptr, H1H, H1M, H1L, 256, 512);
        // ff2: H1 planes @ ff2_w^T -> RES
        k_mfma3<0, 0><<<dim3(64, 2), 256, 0, stream>>>(
            H1H, H1M, H1L, ff2wh + (size_t)l * 131072, ff2wm + (size_t)l * 131072,
            ff2wl + (size_t)l * 131072, ff2_b + l * 256, RES, nullptr, nullptr, nullptr, 512, 256);
        k_add_ln<<<dim3(ROWS), 256, 0, stream>>>(X, RES, ln2_g + l * 256, ln2_b + l * 256, XH, XM, XL);
    }
    // plan = X (+ planes)
    k_mfma3<0, 0><<<dim3(64, 2), 256, 0, stream>>>(
        XH, XM, XL, logwh, logwm, logwl, log_b, PLOG, nullptr, nullptr, nullptr, 256, 256);
    k_mfma3<0, 0><<<dim3(64, 2), 256, 0, stream>>>(
        XH, XM, XL, matwh, matwm, matwl, mat_b, PMAT, nullptr, nullptr, nullptr, 256, 256);
    k_aext3<<<dim3(ROWS), 256, 0, stream>>>(XH, XM, XL, AEH, AEM, AEL);
    k_lif<<<dim3(Bc), 256, 0, stream>>>(PLOG, COMB, 0);
    k_lif<<<dim3(Bc), 256, 0, stream>>>(PMAT, COMB, 256);
    // conv as GEMM: AE planes [8192,768] @ W2^T -> RES (ling)
    k_mfma3<0, 0><<<dim3(64, 2), 256, 0, stream>>>(
        AEH, AEM, AEL, w2h, w2m, w2l, conv_b, RES, nullptr, nullptr, nullptr, 768, 256);
    k_pack<<<dim3(ROWS), 256, 0, stream>>>(RES, X, COMB);
    k_head<<<dim3(64, 63), 256, 0, stream>>>(COMB, HWB, head_b, logits);
    k_pmean<<<dim3(Bc), 256, 0, stream>>>(X, PM);
    k_memread<<<dim3(Bc), 256, 0, stream>>>(PM, read_w, read_b, memory, mread);
}